// Round 18
// baseline (1118.623 us; speedup 1.0000x reference)
//
#include <hip/hip_runtime.h>

// FusedLoRAQKV on MI355X (gfx950).
// Y_p = X @ (W_p + 2 * B_p @ A_p)^T  for p in {Q,K,V}
//
// Pipeline:
//   1. prep:  ONE launch = merge_w3 (blocks 0..6143) + cvt_x (6144..8191).
//   2. gemm:  256x256, BK=64, 8 waves, 16x16x32 MFMA, XOR-swizzled LDS,
//             z-seq XCD remap, LDS-transposed nt epilogue (R13/R17 wins),
//             + CROSS-PHASE READ-AHEAD K-loop: phase = {BAR; stage; [vmcnt];
//             MFMA(operands read LAST phase); reads(next chunk)}. MFMA no
//             longer waits on same-window reads (R13's exposed ~150cyc LDS
//             latency per phase). R4's audited schedule, register-dieted:
//             next-tile B reads moved AFTER Q4's MFMA -> peak live frags
//             24->20 (R4 spilled by ~8 VGPR; this fits 256).
//             vmcnt at END of P3/P7 (before publishing BAR -- single-barrier
//             publication needs all waves drained pre-barrier): vmcnt(2)
//             steady, vmcnt(0) tail.
//
// Closed paths (measured): ordering R6-R10 flat; 32x32 MFMA fixed LDS
// penalty (R3/R11/R12); 2 blocks/CU regressed (R16); fp8 fails absmax.

typedef unsigned short u16;
typedef __attribute__((ext_vector_type(4))) float  f32x4;
typedef __attribute__((ext_vector_type(8))) __bf16 bf16x8;
typedef __attribute__((ext_vector_type(8))) short  s16x8;

#define MDIM 8192
#define NDIM 4096
#define KDIM 4096

__device__ __forceinline__ u16 f2bf(float f) {
    union { float f; unsigned int u; } v;
    v.f = f;
    unsigned int r = v.u + 0x7FFFu + ((v.u >> 16) & 1u);  // RNE
    return (u16)(r >> 16);
}

// ---------------- Kernel 1: fused prep (merge_w3 + cvt_x) ----------------
__global__ void __launch_bounds__(256) prep_kernel(const float* __restrict__ X,
                                                   const float* __restrict__ QW,
                                                   const float* __restrict__ QA,
                                                   const float* __restrict__ QB,
                                                   const float* __restrict__ KW,
                                                   const float* __restrict__ KA,
                                                   const float* __restrict__ KB,
                                                   const float* __restrict__ VW,
                                                   const float* __restrict__ VA,
                                                   const float* __restrict__ VB,
                                                   u16* __restrict__ Xb,
                                                   u16* __restrict__ WbAll) {
    const int bid = blockIdx.x;
    const int t   = threadIdx.x;

    if (bid >= 6144) {
        const int nvec8  = (MDIM * KDIM) / 8;
        const int stride = 2048 * 256;
        for (int i = (bid - 6144) * 256 + t; i < nvec8; i += stride) {
            f32x4 x0 = ((const f32x4*)X)[2 * i];
            f32x4 x1 = ((const f32x4*)X)[2 * i + 1];
            s16x8 o;
            o[0] = (short)f2bf(x0[0]); o[1] = (short)f2bf(x0[1]);
            o[2] = (short)f2bf(x0[2]); o[3] = (short)f2bf(x0[3]);
            o[4] = (short)f2bf(x1[0]); o[5] = (short)f2bf(x1[1]);
            o[6] = (short)f2bf(x1[2]); o[7] = (short)f2bf(x1[3]);
            ((s16x8*)Xb)[i] = o;
        }
        return;
    }

    const int z   = bid >> 11;
    const int rem = bid & 2047;
    const int hb  = (rem & 63) * 64;
    const int nb  = (rem >> 6) * 128;
    const float* W  = (z == 0) ? QW : (z == 1) ? KW : VW;
    const float* A  = (z == 0) ? QA : (z == 1) ? KA : VA;
    const float* Bm = (z == 0) ? QB : (z == 1) ? KB : VB;
    u16* Wb = WbAll + (size_t)z * NDIM * KDIM;

    __shared__ float As[16][64];
    {
        int r = t >> 4, c = (t & 15) * 4;
        *(f32x4*)&As[r][c] = *(const f32x4*)&A[r * 4096 + hb + c];
    }
    __syncthreads();

    const int hl = (t & 7) * 8;
    const int n0 = nb + (t >> 3) * 4;

    float bv[4][16];
    float s[4][8];
#pragma unroll
    for (int i = 0; i < 4; i++) {
        const float* br = &Bm[(size_t)(n0 + i) * 16];
#pragma unroll
        for (int r = 0; r < 16; r++) bv[i][r] = 2.0f * br[r];
        f32x4 w0 = *(const f32x4*)&W[(size_t)(n0 + i) * 4096 + hb + hl];
        f32x4 w1 = *(const f32x4*)&W[(size_t)(n0 + i) * 4096 + hb + hl + 4];
        s[i][0] = w0[0]; s[i][1] = w0[1]; s[i][2] = w0[2]; s[i][3] = w0[3];
        s[i][4] = w1[0]; s[i][5] = w1[1]; s[i][6] = w1[2]; s[i][7] = w1[3];
    }
#pragma unroll
    for (int r = 0; r < 16; r++) {
        f32x4 a0 = *(const f32x4*)&As[r][hl];
        f32x4 a1 = *(const f32x4*)&As[r][hl + 4];
#pragma unroll
        for (int i = 0; i < 4; i++) {
            s[i][0] += bv[i][r] * a0[0]; s[i][1] += bv[i][r] * a0[1];
            s[i][2] += bv[i][r] * a0[2]; s[i][3] += bv[i][r] * a0[3];
            s[i][4] += bv[i][r] * a1[0]; s[i][5] += bv[i][r] * a1[1];
            s[i][6] += bv[i][r] * a1[2]; s[i][7] += bv[i][r] * a1[3];
        }
    }
#pragma unroll
    for (int i = 0; i < 4; i++) {
        s16x8 o;
#pragma unroll
        for (int j = 0; j < 8; j++) o[j] = (short)f2bf(s[i][j]);
        *(s16x8*)&Wb[(size_t)(n0 + i) * 4096 + hb + hl] = o;
    }
}

// ---------------- Kernel 2: 256x256 read-ahead GEMM ----------------
// Per tile T (4 phases); quadrants Q1=aR1xbR01, Q2=aR1xbR23, Q3=aR2xbR01,
// Q4=aR2xbR23. All MFMA operands are read >= 1 phase before consumption:
//   P1: BAR; stg; rd aR2[0,1](T);  Q1
//   P2: BAR; stg; rd aR2[2,3](T);  Q2
//   P3: BAR; stg; vmcnt(2);        Q3
//   P4: BAR; stg; rd aR1(T+1);     Q4; rd bR(T+1)
// Stage slots (pair T,T+1 -- R13-proven): P1: A(T+1).Ah1 | P3: B(T+2).Bh0 |
// P4: B(T+2).Bh1 | P5: A(T+2).Ah0 | P6: A(T+2).Ah1 | P7: B(T+3).Bh0 |
// P8: B(T+3).Bh1 + A(T+3).Ah0.
// LDS-cell WAR: a buffer's cells are free once its ds_reads DRAIN (lgkm
// before the consuming MFMA's phase-end), not when registers are consumed;
// each buffer re-staged >= 1 barrier after its reads drain (R4 audit).
// vmcnt audit: carry into P1 = 6 (B(T+1) 4 + A(T+1).Ah0 2). P3-end: 6+2+2
// = 10 in flight -> vmcnt(2) drains B(T+1)+A(T+1) (read in P4) BEFORE
// BAR(P4) publishes. P7-end: 2+2+2+2+2 = 10 -> vmcnt(2) drains
// B(T+2)+A(T+2). Tail uses vmcnt(0).

#define BM 256
#define BN 256
#define BK 64

#define BAR() asm volatile("s_barrier" ::: "memory")
#define WAIT_VM(n) asm volatile("s_waitcnt vmcnt(" #n ")" ::: "memory")
#define PRIO(p) __builtin_amdgcn_s_setprio(p)

__global__ void __launch_bounds__(512, 2) gemm8_kernel(const u16* __restrict__ Xb,
                                                       const u16* __restrict__ Wb,
                                                       float* __restrict__ out) {
    extern __shared__ char lds[];

    const int t    = threadIdx.x;
    const int lane = t & 63;
    const int w    = t >> 6;      // wave 0..7
    const int wr   = w >> 2;      // M wave 0..1
    const int wn   = w & 3;       // N wave 0..3
    const int lr   = lane & 15;
    const int lkq  = lane >> 4;
    const int lr7  = lr & 7;

    // Z-sequential XCD-bijective remap (R8)
    const int orig = blockIdx.x;
    const int z    = orig >> 9;
    const int r0   = orig & 511;
    const int i_   = (r0 & 7) * 64 + (r0 >> 3);
    const int nT = i_ & 15;
    const int mT = i_ >> 4;
    const int mBase = mT * BM;
    const int nBase = nT * BN;

    const u16* Wp = Wb + (size_t)z * NDIM * KDIM;
    const char* gA = (const char*)Xb + (size_t)mBase * (KDIM * 2);
    const char* gB = (const char*)Wp + (size_t)nBase * (KDIM * 2);

    char* ldsA0 = lds;
    char* ldsA1 = lds + 32768;
    char* ldsB0 = lds + 65536;
    char* ldsB1 = lds + 98304;

    // staging: 2 x global_load_lds(16B)/wave/half-tile, linear LDS dst,
    // pre-swizzled global source column (involution, rule 21)
    const int blkrow = lane >> 3;
    const int colswz = ((lane & 7) ^ blkrow) << 4;
    const size_t stg0 = (size_t)(((w << 1) | 0) * 8 + blkrow) * (KDIM * 2) + colswz;
    const size_t stg1 = (size_t)(((w << 1) | 1) * 8 + blkrow) * (KDIM * 2) + colswz;
    const int ldsStg0 = (((w << 1) | 0) << 10) + lane * 16;
    const int ldsStg1 = (((w << 1) | 1) << 10) + lane * 16;

#define STAGE(ldsTile, gtile, h, kt)                                              \
  { __builtin_amdgcn_global_load_lds(                                             \
        (const __attribute__((address_space(1))) void*)((gtile) + stg0 +          \
            (size_t)(h) * (128 * KDIM * 2) + (size_t)(kt) * 128),                 \
        (__attribute__((address_space(3))) void*)((ldsTile) + (h) * 16384 + ldsStg0), \
        16, 0, 0);                                                                \
    __builtin_amdgcn_global_load_lds(                                             \
        (const __attribute__((address_space(1))) void*)((gtile) + stg1 +          \
            (size_t)(h) * (128 * KDIM * 2) + (size_t)(kt) * 128),                 \
        (__attribute__((address_space(3))) void*)((ldsTile) + (h) * 16384 + ldsStg1), \
        16, 0, 0); }

    // ds_read: row*128 + (((kk<<2)|lkq) ^ (row&7))*16 ; row&7 == lr7
    const int csA = (lkq << 4) ^ (lr7 << 4);
    const int rA0 = (wr * 128 + lr) * 128;
    const int rB0 = (wn * 64 + lr) * 128;
#define RD_A(tile, mi, kk) (*(const bf16x8*)((tile) + rA0 + (mi) * 2048 + (((kk) << 6) ^ csA)))
#define RD_B(tile, ni, kk) (*(const bf16x8*)((tile) + rB0 + (ni) * 2048 + (((kk) << 6) ^ csA)))

    f32x4 acc[8][4] = {};
    bf16x8 aR1[4][2], aR2[4][2], bR[4][2];

#define MFMA_Q(AF, mbase, nbase)                                                   \
    PRIO(1);                                                                       \
    _Pragma("unroll") for (int mi = 0; mi < 4; ++mi)                               \
    _Pragma("unroll") for (int ni = 0; ni < 2; ++ni)                               \
    _Pragma("unroll") for (int kk = 0; kk < 2; ++kk)                               \
      acc[(mbase) + mi][(nbase) + ni] = __builtin_amdgcn_mfma_f32_16x16x32_bf16(   \
          AF[mi][kk], bR[(nbase) + ni][kk], acc[(mbase) + mi][(nbase) + ni], 0, 0, 0); \
    PRIO(0);

// P1: BAR; stage; rd aR2[0,1](T); Q1 (operands from prev P4)
#define PH1(pA, STG)                                                               \
  { BAR(); STG;                                                                    \
    aR2[0][0] = RD_A(pA, 4, 0); aR2[0][1] = RD_A(pA, 4, 1);                        \
    aR2[1][0] = RD_A(pA, 5, 0); aR2[1][1] = RD_A(pA, 5, 1);                        \
    MFMA_Q(aR1, 0, 0) }

// P2: BAR; stage; rd aR2[2,3](T); Q2
#define PH2(pA, STG)                                                               \
  { BAR(); STG;                                                                    \
    aR2[2][0] = RD_A(pA, 6, 0); aR2[2][1] = RD_A(pA, 6, 1);                        \
    aR2[3][0] = RD_A(pA, 7, 0); aR2[3][1] = RD_A(pA, 7, 1);                        \
    MFMA_Q(aR1, 0, 2) }

// P3: BAR; stage; vmcnt (pre-publication drain, before BAR(P4)); Q3
#define PH3(STG, VMW)                                                              \
  { BAR(); STG; VMW; MFMA_Q(aR2, 4, 0) }

// P4: BAR; stage; rd aR1(T+1); Q4; rd bR(T+1) (after MFMA -- liveness diet)
#define PH4(pAn, pBn, STG)                                                         \
  { BAR(); STG;                                                                    \
    _Pragma("unroll") for (int mi = 0; mi < 4; ++mi) {                             \
      aR1[mi][0] = RD_A(pAn, mi, 0); aR1[mi][1] = RD_A(pAn, mi, 1); }              \
    MFMA_Q(aR2, 4, 2)                                                              \
    bR[0][0] = RD_B(pBn, 0, 0); bR[0][1] = RD_B(pBn, 0, 1);                        \
    bR[1][0] = RD_B(pBn, 1, 0); bR[1][1] = RD_B(pBn, 1, 1);                        \
    bR[2][0] = RD_B(pBn, 2, 0); bR[2][1] = RD_B(pBn, 2, 1);                        \
    bR[3][0] = RD_B(pBn, 3, 0); bR[3][1] = RD_B(pBn, 3, 1); }

#define PH4F()                                                                     \
  { BAR(); MFMA_Q(aR2, 4, 2) }

    // ---- prologue: A(0), B(0), B(1), A(1).Ah0 = 14 loads; pre-read tile 0 ----
    STAGE(ldsA0, gA, 0, 0); STAGE(ldsA0, gA, 1, 0);
    STAGE(ldsB0, gB, 0, 0); STAGE(ldsB0, gB, 1, 0);
    STAGE(ldsB1, gB, 0, 1); STAGE(ldsB1, gB, 1, 1);
    STAGE(ldsA1, gA, 0, 1);
    WAIT_VM(6);   // drain A(0)+B(0); leftover 6 = B(1)+A(1).Ah0 = steady carry
    BAR();
#pragma unroll
    for (int mi = 0; mi < 4; ++mi) {
        aR1[mi][0] = RD_A(ldsA0, mi, 0); aR1[mi][1] = RD_A(ldsA0, mi, 1);
    }
#pragma unroll
    for (int ni = 0; ni < 4; ++ni) {
        bR[ni][0] = RD_B(ldsB0, ni, 0); bR[ni][1] = RD_B(ldsB0, ni, 1);
    }

    // ---- main loop: 31 iterations (tiles T=2i, T+1), T = 0..60 ----
    for (int i = 0; i < 31; ++i) {
        const int T = 2 * i;
        PH1(ldsA0,        STAGE(ldsA1, gA, 1, T + 1));                  // A(T+1).Ah1
        PH2(ldsA0, );                                                   // no stage
        PH3(              STAGE(ldsB0, gB, 0, T + 2), WAIT_VM(2));      // B(T+2).Bh0
        PH4(ldsA1, ldsB1, STAGE(ldsB0, gB, 1, T + 2));                  // B(T+2).Bh1; RA T+1
        PH1(ldsA1,        STAGE(ldsA0, gA, 0, T + 2));                  // A(T+2).Ah0
        PH2(ldsA1,        STAGE(ldsA0, gA, 1, T + 2));                  // A(T+2).Ah1
        PH3(              STAGE(ldsB1, gB, 0, T + 3), WAIT_VM(2));      // B(T+3).Bh0
        PH4(ldsA0, ldsB0, { STAGE(ldsB1, gB, 1, T + 3)                  // B(T+3).Bh1
                            STAGE(ldsA1, gA, 0, T + 3) });              // A(T+3).Ah0; RA T+2
    }

    // ---- peeled last pair (tiles 62, 63) ----
    PH1(ldsA0,        STAGE(ldsA1, gA, 1, 63));                         // A(63).Ah1
    PH2(ldsA0, );
    PH3( , WAIT_VM(0));                                                 // drain all
    PH4(ldsA1, ldsB1, );                                                // RA tile 63
    PH1(ldsA1, );
    PH2(ldsA1, );
    PH3( , );
    PH4F();

    // ---- epilogue: LDS-transpose + full-line nontemporal stores ----
    // __syncthreads() (NOT raw s_barrier): acc->LDS ds_writes have no
    // in-wave consumer -> raw barrier has no preceding lgkm wait (R15 race).
    __syncthreads();
    float* C    = out + (size_t)z * MDIM * NDIM;
    float* ldsf = (float*)lds;                    // f32 [128][256] = 128 KiB
#pragma unroll
    for (int round = 0; round < 2; ++round) {
        if (wr == round) {
#pragma unroll
            for (int mi = 0; mi < 8; ++mi) {
#pragma unroll
                for (int ni = 0; ni < 4; ++ni) {
                    const int lrow = mi * 16 + lkq * 4;
                    const int col  = wn * 64 + ni * 16 + lr;
                    f32x4 v = acc[mi][ni];
#pragma unroll
                    for (int j = 0; j < 4; ++j)
                        ldsf[(lrow + j) * 256 + col] = v[j];
                }
            }
        }
        __syncthreads();
        const size_t gb = (size_t)(mBase + round * 128) * NDIM + nBase;
#pragma unroll
        for (int rr = 0; rr < 16; ++rr) {
            const int row = w * 16 + rr;
            f32x4 v = *(const f32x4*)&ldsf[row * 256 + lane * 4];
            __builtin_nontemporal_store(v,
                (f32x4*)(C + gb + (size_t)row * NDIM + lane * 4));
        }
        __syncthreads();
    }
}

// ---------------- host launch ----------------
extern "C" void kernel_launch(void* const* d_in, const int* in_sizes, int n_in,
                              void* d_out, int out_size, void* d_ws, size_t ws_size,
                              hipStream_t stream) {
    const float* X  = (const float*)d_in[0];
    const float* QW = (const float*)d_in[1];
    const float* QA = (const float*)d_in[2];
    const float* QB = (const float*)d_in[3];
    const float* KW = (const float*)d_in[4];
    const float* KA = (const float*)d_in[5];
    const float* KB = (const float*)d_in[6];
    const float* VW = (const float*)d_in[7];
    const float* VA = (const float*)d_in[8];
    const float* VB = (const float*)d_in[9];
    float* out = (float*)d_out;

    u16* Xb = (u16*)d_ws;                                        // 64 MiB
    u16* Wb = (u16*)((char*)d_ws + (size_t)MDIM * KDIM * 2);     // 3 x 32 MiB

    (void)hipFuncSetAttribute((const void*)gemm8_kernel,
                              hipFuncAttributeMaxDynamicSharedMemorySize, 131072);

    prep_kernel<<<8192, 256, 0, stream>>>(X, QW, QA, QB, KW, KA, KB,
                                          VW, VA, VB, Xb, Wb);

    gemm8_kernel<<<dim3(16 * 32 * 3), dim3(512), 131072, stream>>>(Xb, Wb, out);
}

// Round 19
// 733.046 us; speedup vs baseline: 1.5260x; 1.5260x over previous
//
#include <hip/hip_runtime.h>

// FusedLoRAQKV on MI355X (gfx950).
// Y_p = X @ (W_p + 2 * B_p @ A_p)^T  for p in {Q,K,V}
//
// FINAL (R17 structure -- best of 18 rounds, 738us):
//   1. prep:  ONE launch = merge_w3 (blocks 0..6143) + cvt_x (6144..8191).
//   2. gemm:  256x256 tile, BK=64, 8 waves, mfma_f32_16x16x32_bf16,
//             XOR-swizzled LDS (0 conflicts), single-barrier phases
//             {BAR; reads; stage; MFMA}, 12/8/4/0 reads,
//             vmcnt(4)@P4/vmcnt(6)@P8, z-seq XCD remap, LDS-transposed
//             epilogue with full-line nt stores, __syncthreads in epilogue
//             (ds_writes need the full lgkm drain before cross-wave read).
//
// Closed paths (all measured): phase-ordering variants flat (R6/R9/R10);
// 32x32 MFMA carries a fixed swizzle-invariant LDS penalty (R3/R11/R12);
// occupancy restructuring regressed (R14/R16); cross-phase read-ahead
// spills the 256-reg budget (R3/R4/R18 -- 128-AGPR acc + 20 live operand
// frags + state > 256). Residual gap to m201-class is register-infeasible
// at HIP source level for this acc footprint.

typedef unsigned short u16;
typedef __attribute__((ext_vector_type(4))) float  f32x4;
typedef __attribute__((ext_vector_type(8))) __bf16 bf16x8;
typedef __attribute__((ext_vector_type(8))) short  s16x8;

#define MDIM 8192
#define NDIM 4096
#define KDIM 4096

__device__ __forceinline__ u16 f2bf(float f) {
    union { float f; unsigned int u; } v;
    v.f = f;
    unsigned int r = v.u + 0x7FFFu + ((v.u >> 16) & 1u);  // RNE
    return (u16)(r >> 16);
}

// ---------------- Kernel 1: fused prep (merge_w3 + cvt_x) ----------------
__global__ void __launch_bounds__(256) prep_kernel(const float* __restrict__ X,
                                                   const float* __restrict__ QW,
                                                   const float* __restrict__ QA,
                                                   const float* __restrict__ QB,
                                                   const float* __restrict__ KW,
                                                   const float* __restrict__ KA,
                                                   const float* __restrict__ KB,
                                                   const float* __restrict__ VW,
                                                   const float* __restrict__ VA,
                                                   const float* __restrict__ VB,
                                                   u16* __restrict__ Xb,
                                                   u16* __restrict__ WbAll) {
    const int bid = blockIdx.x;
    const int t   = threadIdx.x;

    if (bid >= 6144) {
        const int nvec8  = (MDIM * KDIM) / 8;
        const int stride = 2048 * 256;
        for (int i = (bid - 6144) * 256 + t; i < nvec8; i += stride) {
            f32x4 x0 = ((const f32x4*)X)[2 * i];
            f32x4 x1 = ((const f32x4*)X)[2 * i + 1];
            s16x8 o;
            o[0] = (short)f2bf(x0[0]); o[1] = (short)f2bf(x0[1]);
            o[2] = (short)f2bf(x0[2]); o[3] = (short)f2bf(x0[3]);
            o[4] = (short)f2bf(x1[0]); o[5] = (short)f2bf(x1[1]);
            o[6] = (short)f2bf(x1[2]); o[7] = (short)f2bf(x1[3]);
            ((s16x8*)Xb)[i] = o;
        }
        return;
    }

    const int z   = bid >> 11;
    const int rem = bid & 2047;
    const int hb  = (rem & 63) * 64;
    const int nb  = (rem >> 6) * 128;
    const float* W  = (z == 0) ? QW : (z == 1) ? KW : VW;
    const float* A  = (z == 0) ? QA : (z == 1) ? KA : VA;
    const float* Bm = (z == 0) ? QB : (z == 1) ? KB : VB;
    u16* Wb = WbAll + (size_t)z * NDIM * KDIM;

    __shared__ float As[16][64];
    {
        int r = t >> 4, c = (t & 15) * 4;
        *(f32x4*)&As[r][c] = *(const f32x4*)&A[r * 4096 + hb + c];
    }
    __syncthreads();

    const int hl = (t & 7) * 8;
    const int n0 = nb + (t >> 3) * 4;

    float bv[4][16];
    float s[4][8];
#pragma unroll
    for (int i = 0; i < 4; i++) {
        const float* br = &Bm[(size_t)(n0 + i) * 16];
#pragma unroll
        for (int r = 0; r < 16; r++) bv[i][r] = 2.0f * br[r];
        f32x4 w0 = *(const f32x4*)&W[(size_t)(n0 + i) * 4096 + hb + hl];
        f32x4 w1 = *(const f32x4*)&W[(size_t)(n0 + i) * 4096 + hb + hl + 4];
        s[i][0] = w0[0]; s[i][1] = w0[1]; s[i][2] = w0[2]; s[i][3] = w0[3];
        s[i][4] = w1[0]; s[i][5] = w1[1]; s[i][6] = w1[2]; s[i][7] = w1[3];
    }
#pragma unroll
    for (int r = 0; r < 16; r++) {
        f32x4 a0 = *(const f32x4*)&As[r][hl];
        f32x4 a1 = *(const f32x4*)&As[r][hl + 4];
#pragma unroll
        for (int i = 0; i < 4; i++) {
            s[i][0] += bv[i][r] * a0[0]; s[i][1] += bv[i][r] * a0[1];
            s[i][2] += bv[i][r] * a0[2]; s[i][3] += bv[i][r] * a0[3];
            s[i][4] += bv[i][r] * a1[0]; s[i][5] += bv[i][r] * a1[1];
            s[i][6] += bv[i][r] * a1[2]; s[i][7] += bv[i][r] * a1[3];
        }
    }
#pragma unroll
    for (int i = 0; i < 4; i++) {
        s16x8 o;
#pragma unroll
        for (int j = 0; j < 8; j++) o[j] = (short)f2bf(s[i][j]);
        *(s16x8*)&Wb[(size_t)(n0 + i) * 4096 + hb + hl] = o;
    }
}

// ---------------- Kernel 2: 256x256 single-barrier-phase GEMM ----------------
// 8 waves (2M x 4N), per-wave 128x64 out, acc[8][4] f32x4 (16x16x32 MFMA).
// LDS 128 KiB: A[2][256][64] + B[2][256][64] bf16, 16B-chunk XOR swizzle
// (chunk ^= row&7), linear-dst global_load_lds + pre-swizzled source.
//
// Phase = { BAR ; ds_reads ; stage ; [vmcnt] ; MFMA }.  ONE barrier/phase.
//   P1: rd 12 (aR1, bR01); STG; Q1   P2: rd 8 (b23, aR2a); STG; Q2
//   P3: rd 4  (aR2b);      STG; Q3   P4: STG; vmcnt; Q4
// WAR/vmcnt audits (R7/R8-verified): A-buf staged P5/P6 (last read P3);
// B-buf staged P3/P4 (last read P2); carry into P1 = 6; P4: vmcnt(4);
// P8: vmcnt(6). K-loop raw BARs safe: every ds_read is lgkm-consumed by an
// MFMA before its wave reaches the next BAR; stages vmcnt-drained pre-BAR.

#define BM 256
#define BN 256
#define BK 64

#define BAR() asm volatile("s_barrier" ::: "memory")
#define WAIT_VM(n) asm volatile("s_waitcnt vmcnt(" #n ")" ::: "memory")
#define PRIO(p) __builtin_amdgcn_s_setprio(p)

__global__ void __launch_bounds__(512, 2) gemm8_kernel(const u16* __restrict__ Xb,
                                                       const u16* __restrict__ Wb,
                                                       float* __restrict__ out) {
    extern __shared__ char lds[];

    const int t    = threadIdx.x;
    const int lane = t & 63;
    const int w    = t >> 6;      // wave 0..7
    const int wr   = w >> 2;      // M wave 0..1
    const int wn   = w & 3;      // N wave 0..3
    const int lr   = lane & 15;
    const int lkq  = lane >> 4;
    const int lr7  = lr & 7;

    // Z-sequential XCD-bijective remap (R8): z = orig/512 sequential bands;
    // within z: i = (r&7)*64 + r/8 (bijective, 512 = 8 x 64).
    const int orig = blockIdx.x;
    const int z    = orig >> 9;
    const int r0   = orig & 511;
    const int i_   = (r0 & 7) * 64 + (r0 >> 3);
    const int nT = i_ & 15;
    const int mT = i_ >> 4;
    const int mBase = mT * BM;
    const int nBase = nT * BN;

    const u16* Wp = Wb + (size_t)z * NDIM * KDIM;
    const char* gA = (const char*)Xb + (size_t)mBase * (KDIM * 2);
    const char* gB = (const char*)Wp + (size_t)nBase * (KDIM * 2);

    char* ldsA0 = lds;
    char* ldsA1 = lds + 32768;
    char* ldsB0 = lds + 65536;
    char* ldsB1 = lds + 98304;

    // staging: 2 x global_load_lds(16B)/wave/half-tile, linear LDS dst,
    // pre-swizzled global source column (involution, rule 21)
    const int blkrow = lane >> 3;
    const int colswz = ((lane & 7) ^ blkrow) << 4;
    const size_t stg0 = (size_t)(((w << 1) | 0) * 8 + blkrow) * (KDIM * 2) + colswz;
    const size_t stg1 = (size_t)(((w << 1) | 1) * 8 + blkrow) * (KDIM * 2) + colswz;
    const int ldsStg0 = (((w << 1) | 0) << 10) + lane * 16;
    const int ldsStg1 = (((w << 1) | 1) << 10) + lane * 16;

#define STAGE(ldsTile, gtile, h, kt)                                              \
  { __builtin_amdgcn_global_load_lds(                                             \
        (const __attribute__((address_space(1))) void*)((gtile) + stg0 +          \
            (size_t)(h) * (128 * KDIM * 2) + (size_t)(kt) * 128),                 \
        (__attribute__((address_space(3))) void*)((ldsTile) + (h) * 16384 + ldsStg0), \
        16, 0, 0);                                                                \
    __builtin_amdgcn_global_load_lds(                                             \
        (const __attribute__((address_space(1))) void*)((gtile) + stg1 +          \
            (size_t)(h) * (128 * KDIM * 2) + (size_t)(kt) * 128),                 \
        (__attribute__((address_space(3))) void*)((ldsTile) + (h) * 16384 + ldsStg1), \
        16, 0, 0); }

    // ds_read: row*128 + (((kk<<2)|lkq) ^ (row&7))*16 ; row&7 == lr7
    const int csA = (lkq << 4) ^ (lr7 << 4);
    const int rA0 = (wr * 128 + lr) * 128;
    const int rB0 = (wn * 64 + lr) * 128;
#define RD_A(tile, mi, kk) (*(const bf16x8*)((tile) + rA0 + (mi) * 2048 + (((kk) << 6) ^ csA)))
#define RD_B(tile, ni, kk) (*(const bf16x8*)((tile) + rB0 + (ni) * 2048 + (((kk) << 6) ^ csA)))

    f32x4 acc[8][4] = {};
    bf16x8 aR1[4][2], aR2[4][2], bR[4][2];

#define MFMA_Q(AF, mbase, nbase)                                                   \
    PRIO(1);                                                                       \
    _Pragma("unroll") for (int mi = 0; mi < 4; ++mi)                               \
    _Pragma("unroll") for (int ni = 0; ni < 2; ++ni)                               \
    _Pragma("unroll") for (int kk = 0; kk < 2; ++kk)                               \
      acc[(mbase) + mi][(nbase) + ni] = __builtin_amdgcn_mfma_f32_16x16x32_bf16(   \
          AF[mi][kk], bR[(nbase) + ni][kk], acc[(mbase) + mi][(nbase) + ni], 0, 0, 0); \
    PRIO(0);

#define PH1(pA, pB, STG)                                                           \
  { BAR();                                                                         \
    aR1[0][0] = RD_A(pA, 0, 0); aR1[0][1] = RD_A(pA, 0, 1);                        \
    bR[0][0]  = RD_B(pB, 0, 0); bR[0][1]  = RD_B(pB, 0, 1);                        \
    aR1[1][0] = RD_A(pA, 1, 0); aR1[1][1] = RD_A(pA, 1, 1);                        \
    bR[1][0]  = RD_B(pB, 1, 0); bR[1][1]  = RD_B(pB, 1, 1);                        \
    aR1[2][0] = RD_A(pA, 2, 0); aR1[2][1] = RD_A(pA, 2, 1);                        \
    aR1[3][0] = RD_A(pA, 3, 0); aR1[3][1] = RD_A(pA, 3, 1);                        \
    STG; MFMA_Q(aR1, 0, 0) }

#define PH2(pA, pB, STG)                                                           \
  { BAR();                                                                         \
    bR[2][0] = RD_B(pB, 2, 0); bR[2][1] = RD_B(pB, 2, 1);                          \
    bR[3][0] = RD_B(pB, 3, 0); bR[3][1] = RD_B(pB, 3, 1);                          \
    aR2[0][0] = RD_A(pA, 4, 0); aR2[0][1] = RD_A(pA, 4, 1);                        \
    aR2[1][0] = RD_A(pA, 5, 0); aR2[1][1] = RD_A(pA, 5, 1);                        \
    STG; MFMA_Q(aR1, 0, 2) }

#define PH3(pA, STG)                                                               \
  { BAR();                                                                         \
    aR2[2][0] = RD_A(pA, 6, 0); aR2[2][1] = RD_A(pA, 6, 1);                        \
    aR2[3][0] = RD_A(pA, 7, 0); aR2[3][1] = RD_A(pA, 7, 1);                        \
    STG; MFMA_Q(aR2, 4, 0) }

#define PH4(STG, VMW)                                                              \
  { BAR(); STG; VMW; MFMA_Q(aR2, 4, 2) }

#define PH4F()                                                                     \
  { BAR(); MFMA_Q(aR2, 4, 2) }

    // ---- prologue: A(0) full, B(0) full, B(1) full, A(1).Ah0 = 14 loads ----
    STAGE(ldsA0, gA, 0, 0); STAGE(ldsA0, gA, 1, 0);
    STAGE(ldsB0, gB, 0, 0); STAGE(ldsB0, gB, 1, 0);
    STAGE(ldsB1, gB, 0, 1); STAGE(ldsB1, gB, 1, 1);
    STAGE(ldsA1, gA, 0, 1);
    WAIT_VM(6);   // drain A(0)+B(0); leftover 6 = B(1)+A(1).Ah0 = steady carry

    // ---- main loop: 31 iterations (tiles T=2i, T+1), T = 0..60 ----
    for (int i = 0; i < 31; ++i) {
        const int T = 2 * i;
        PH1(ldsA0, ldsB0, STAGE(ldsA1, gA, 1, T + 1));                   // A(T+1).Ah1
        PH2(ldsA0, ldsB0, );                                             // no stage
        PH3(ldsA0,        STAGE(ldsB0, gB, 0, T + 2));                   // B(T+2).Bh0
        PH4(              STAGE(ldsB0, gB, 1, T + 2), WAIT_VM(4));       // B(T+2).Bh1
        PH1(ldsA1, ldsB1, STAGE(ldsA0, gA, 0, T + 2));                   // A(T+2).Ah0
        PH2(ldsA1, ldsB1, STAGE(ldsA0, gA, 1, T + 2));                   // A(T+2).Ah1
        PH3(ldsA1,        STAGE(ldsB1, gB, 0, T + 3));                   // B(T+3).Bh0
        PH4(              { STAGE(ldsB1, gB, 1, T + 3)                   // B(T+3).Bh1
                            STAGE(ldsA1, gA, 0, T + 3) }, WAIT_VM(6));   // A(T+3).Ah0
    }

    // ---- peeled last pair (tiles 62, 63) ----
    PH1(ldsA0, ldsB0, STAGE(ldsA1, gA, 1, 63));                          // A(63).Ah1
    PH2(ldsA0, ldsB0, );
    PH3(ldsA0, );
    PH4(, WAIT_VM(0));                                                   // all landed
    PH1(ldsA1, ldsB1, );
    PH2(ldsA1, ldsB1, );
    PH3(ldsA1, );
    PH4F();

    // ---- epilogue: LDS-transpose + full-line nontemporal stores ----
    // __syncthreads() (NOT raw s_barrier): acc->LDS ds_writes have no
    // in-wave consumer -> raw barrier has no preceding lgkm wait (R15 race).
    __syncthreads();
    float* C    = out + (size_t)z * MDIM * NDIM;
    float* ldsf = (float*)lds;                    // f32 [128][256] = 128 KiB
#pragma unroll
    for (int round = 0; round < 2; ++round) {
        if (wr == round) {
#pragma unroll
            for (int mi = 0; mi < 8; ++mi) {
#pragma unroll
                for (int ni = 0; ni < 4; ++ni) {
                    const int lrow = mi * 16 + lkq * 4;
                    const int col  = wn * 64 + ni * 16 + lr;
                    f32x4 v = acc[mi][ni];
#pragma unroll
                    for (int j = 0; j < 4; ++j)
                        ldsf[(lrow + j) * 256 + col] = v[j];
                }
            }
        }
        __syncthreads();
        const size_t gb = (size_t)(mBase + round * 128) * NDIM + nBase;
#pragma unroll
        for (int rr = 0; rr < 16; ++rr) {
            const int row = w * 16 + rr;
            f32x4 v = *(const f32x4*)&ldsf[row * 256 + lane * 4];
            __builtin_nontemporal_store(v,
                (f32x4*)(C + gb + (size_t)row * NDIM + lane * 4));
        }
        __syncthreads();
    }
}

// ---------------- host launch ----------------
extern "C" void kernel_launch(void* const* d_in, const int* in_sizes, int n_in,
                              void* d_out, int out_size, void* d_ws, size_t ws_size,
                              hipStream_t stream) {
    const float* X  = (const float*)d_in[0];
    const float* QW = (const float*)d_in[1];
    const float* QA = (const float*)d_in[2];
    const float* QB = (const float*)d_in[3];
    const float* KW = (const float*)d_in[4];
    const float* KA = (const float*)d_in[5];
    const float* KB = (const float*)d_in[6];
    const float* VW = (const float*)d_in[7];
    const float* VA = (const float*)d_in[8];
    const float* VB = (const float*)d_in[9];
    float* out = (float*)d_out;

    u16* Xb = (u16*)d_ws;                                        // 64 MiB
    u16* Wb = (u16*)((char*)d_ws + (size_t)MDIM * KDIM * 2);     // 3 x 32 MiB

    (void)hipFuncSetAttribute((const void*)gemm8_kernel,
                              hipFuncAttributeMaxDynamicSharedMemorySize, 131072);

    prep_kernel<<<8192, 256, 0, stream>>>(X, QW, QA, QB, KW, KA, KB,
                                          VW, VA, VB, Xb, Wb);

    gemm8_kernel<<<dim3(16 * 32 * 3), dim3(512), 131072, stream>>>(Xb, Wb, out);
}